// Round 11
// baseline (528.107 us; speedup 1.0000x reference)
//
#include <hip/hip_runtime.h>
#include <hip/hip_cooperative_groups.h>

// GAT (3-layer) on MI355X. N=50000 nodes, E=800000 edges, D=64, H=2/2/1.
// R11: cooperative mega-kernel, retried. R10's coop launch silently failed
//      (unchecked return; 768 blocks x 34.8KB LDS rejected by the runtime's
//      co-residency model). Fixes: (a) GEMM B-fragments read from global Wt
//      (L1/L2-resident, no LDS tile) -> k_mega LDS = 1KB scan buffer only;
//      (b) grid sized by hipOccupancyMaxActiveBlocksPerMultiprocessor;
//      (c) return-code-checked, with the proven R8 multi-dispatch fallback
//      sharing the same device functions (identical numerics either way).

namespace cg = cooperative_groups;

typedef __attribute__((ext_vector_type(8))) short short8;   // 8 bf16 (4 VGPRs)
typedef __attribute__((ext_vector_type(4))) float float4v;  // 4 fp32 acc

__device__ __forceinline__ float lrelu(float x){ return x >= 0.f ? x : 0.2f*x; }

__device__ __forceinline__ unsigned short f2bf(float f){   // RNE round
  unsigned int u = __float_as_uint(f);
  u += 0x7fffu + ((u >> 16) & 1u);
  return (unsigned short)(u >> 16);
}
__device__ __forceinline__ float bf2f(unsigned short u){
  return __uint_as_float((unsigned int)u << 16);
}
__device__ __forceinline__ float rl_f(float v, int l){
  return __int_as_float(__builtin_amdgcn_readlane(__float_as_int(v), l));
}

// ---- shared phase bodies -------------------------------------------------

__device__ void wprep_body(const float* W0, const float* W1, const float* W2,
                           const float* rW2, unsigned short* Wt0,
                           unsigned short* Wt1, unsigned short* Wt2,
                           int gtid, int gsz){
  for (int id = gtid; id < 128*64 + 2*128*128; id += gsz){
    if (id < 128*64){
      int n = id/64, k = id%64;
      Wt0[n*64 + k] = f2bf(W0[k*128 + n]);
    } else if (id < 128*64 + 128*128){
      int j = id - 128*64; int n = j/128, k = j%128;
      Wt1[n*128 + k] = f2bf(W1[k*128 + n]);
    } else {
      int j = id - 128*64 - 128*128; int n = j/128, k = j%128;
      float v = (n < 64) ? W2[k*64 + n] : rW2[k*64 + (n - 64)];
      Wt2[n*128 + k] = f2bf(v);
    }
  }
}

__device__ void hist_body(const int* dst, int* counts, int E, int gtid, int gsz){
  for (int base = gtid*4; base < E; base += gsz*4){
    #pragma unroll
    for (int u = 0; u < 4; u++){
      int i = base + u;
      if (i < E) atomicAdd(&counts[dst[i]], 1);
    }
  }
}

__device__ void scatter_body(const int* src, const int* dst, const int* row_ptr,
                             int* cursor, unsigned short* ssrc, int E,
                             int gtid, int gsz){
  for (int base = gtid*4; base < E; base += gsz*4){
    #pragma unroll
    for (int u = 0; u < 4; u++){
      int i = base + u;
      if (i < E){
        int d = dst[i];
        int pos = atomicAdd(&cursor[d], 1);
        ssrc[row_ptr[d] + pos] = (unsigned short)src[i];
      }
    }
  }
}

// MFMA GEMM: fhb[N][128](bf16 row-major) = A[N][IN] @ W(128 cols via Wt, global).
// AMODE: 0 = embed (A = emb[feat[row]]*fv[row]), 1 = fp32 global rows.
// Layouts (verified): A[m=lane&15][k=quad*8+j]; B[k=quad*8+j][n=lane&15];
// D: col=lane&15, row=quad*4+reg. el/er fused (16-lane butterfly per quad).
template<int IN, int H, int AMODE>
__device__ void gemm_phase(
    const float* __restrict__ hf,
    const int* __restrict__ feat, const float* __restrict__ fv, const float* __restrict__ emb,
    const unsigned short* __restrict__ Wt,
    const float* __restrict__ al, const float* __restrict__ ar,
    unsigned short* __restrict__ fhb, float* __restrict__ elr,
    int N, int bid, int nb, int t){
  constexpr int KS = IN/32;
  const int lane = t & 63, wid = t >> 6;
  const int l15 = lane & 15, quad = lane >> 4;

  float alc[8], arc[8];
  #pragma unroll
  for (int nt = 0; nt < 8; nt++){
    bool hv = (H == 2) || (nt < 4);
    alc[nt] = hv ? al[nt*16 + l15] : 0.f;
    arc[nt] = hv ? ar[nt*16 + l15] : 0.f;
  }

  const int ntiles = (N + 63)/64;
  for (int tile = bid; tile < ntiles; tile += nb){
    const int row0 = tile*64 + wid*16;
    short8 a[KS];
    int arow = row0 + l15;
    {
      const float* ap = nullptr;
      float sc = 1.f;
      if (AMODE == 0){
        int f = 0; sc = 0.f;
        if (arow < N){ f = feat[arow]; sc = fv[arow]; }
        ap = emb + (size_t)f*64;
      } else {
        ap = (arow < N) ? hf + (size_t)arow*IN : nullptr;
      }
      #pragma unroll
      for (int s = 0; s < KS; s++){
        short8 av = short8{0,0,0,0,0,0,0,0};
        if (ap){
          const float* p = ap + s*32 + quad*8;
          float4 v0 = ((const float4*)p)[0];
          float4 v1 = ((const float4*)p)[1];
          av[0]=(short)f2bf(v0.x*sc); av[1]=(short)f2bf(v0.y*sc);
          av[2]=(short)f2bf(v0.z*sc); av[3]=(short)f2bf(v0.w*sc);
          av[4]=(short)f2bf(v1.x*sc); av[5]=(short)f2bf(v1.y*sc);
          av[6]=(short)f2bf(v1.z*sc); av[7]=(short)f2bf(v1.w*sc);
        }
        a[s] = av;
      }
    }
    float4v acc[8];
    #pragma unroll
    for (int nt = 0; nt < 8; nt++) acc[nt] = float4v{0.f,0.f,0.f,0.f};
    #pragma unroll
    for (int nt = 0; nt < 8; nt++){
      #pragma unroll
      for (int s = 0; s < KS; s++){
        short8 b = *(const short8*)(Wt + (size_t)(nt*16 + l15)*IN + s*32 + quad*8);
        acc[nt] = __builtin_amdgcn_mfma_f32_16x16x32_bf16(a[s], b, acc[nt], 0, 0, 0);
      }
    }
    #pragma unroll
    for (int reg = 0; reg < 4; reg++){
      int row = row0 + quad*4 + reg;
      bool rv = row < N;
      if (rv){
        #pragma unroll
        for (int nt = 0; nt < 8; nt++)
          fhb[(size_t)row*128 + nt*16 + l15] = f2bf(acc[nt][reg]);
      }
      float pel0 = 0.f, per0 = 0.f, pel1 = 0.f, per1 = 0.f;
      #pragma unroll
      for (int nt = 0; nt < 4; nt++){
        pel0 += acc[nt][reg]*alc[nt];     per0 += acc[nt][reg]*arc[nt];
        pel1 += acc[nt+4][reg]*alc[nt+4]; per1 += acc[nt+4][reg]*arc[nt+4];
      }
      #pragma unroll
      for (int off = 1; off < 16; off <<= 1){   // reduce across the quad's 16 lanes
        pel0 += __shfl_xor(pel0, off, 64);
        pel1 += __shfl_xor(pel1, off, 64);
        per0 += __shfl_xor(per0, off, 64);
        per1 += __shfl_xor(per1, off, 64);
      }
      if (l15 == 0 && rv){
        elr[row*4+0] = pel0;
        elr[row*4+1] = (H == 2) ? pel1 : 0.f;
        elr[row*4+2] = per0;
        elr[row*4+3] = (H == 2) ? per1 : 0.f;
      }
    }
  }
}

// agg: R8's proven kernel as device fn, grid-strided.
template<int H>
__device__ void agg_phase(
    const unsigned* __restrict__ fhb, const float* __restrict__ elr,
    const int* __restrict__ row_ptr, const unsigned short* __restrict__ ssrc,
    const float* __restrict__ bias, const float* __restrict__ res,
    int act, int res_from_fh,
    float* __restrict__ out, int out_ld, int N, int bid, int nb, int t){
  const int lane = t & 63, wid = t >> 6;
  for (int n = bid*4 + wid; n < N; n += nb*4){
    int beg = row_ptr[n], end = row_ptr[n+1];
    float er0 = elr[n*4+2];
    float er1 = (H == 2) ? elr[n*4+3] : 0.f;

    float x0 = 0.f, x1 = 0.f;
    {
      int i = beg + lane;
      if (i < end){
        int s = ssrc[i];
        float2 el = *(const float2*)(elr + s*4);
        x0 = __expf(fminf(lrelu(el.x + er0), 30.f));
        if (H == 2) x1 = __expf(fminf(lrelu(el.y + er1), 30.f));
      }
    }
    float d0 = x0, d1 = x1;
    for (int i = beg + lane + 64; i < end; i += 64){
      int s = ssrc[i];
      float2 el = *(const float2*)(elr + s*4);
      d0 += __expf(fminf(lrelu(el.x + er0), 30.f));
      if (H == 2) d1 += __expf(fminf(lrelu(el.y + er1), 30.f));
    }
    #pragma unroll
    for (int off = 32; off >= 1; off >>= 1){
      d0 += __shfl_xor(d0, off, 64);
      if (H == 2) d1 += __shfl_xor(d1, off, 64);
    }
    float rd0 = d0 > 0.f ? 1.f/d0 : 0.f;
    float rd1 = (H == 2 && d1 > 0.f) ? 1.f/d1 : 0.f;

    float ax = 0.f, ay = 0.f;
    for (int base = beg; base < end; base += 64){
      int i = base + lane;
      int s = 0; float a0 = 0.f, a1 = 0.f;
      if (i < end){
        s = ssrc[i];
        if (base == beg){
          a0 = x0 * rd0; if (H == 2) a1 = x1 * rd1;
        } else {
          float2 el = *(const float2*)(elr + s*4);
          a0 = __expf(fminf(lrelu(el.x + er0), 30.f)) * rd0;
          if (H == 2) a1 = __expf(fminf(lrelu(el.y + er1), 30.f)) * rd1;
        }
      }
      int cnt = min(64, end - base);
      int j0 = 0;
      if (H == 2){
        for (; j0 + 16 <= cnt; j0 += 16){
          unsigned w[16]; float aj[16];
          #pragma unroll
          for (int u = 0; u < 16; u++){
            int sj = __builtin_amdgcn_readlane(s, j0 + u);    // SGPR: scalar addr
            w[u] = fhb[(size_t)sj*64 + lane];                 // cols 2l,2l+1
          }
          #pragma unroll
          for (int u = 0; u < 16; u++){
            float aj0 = rl_f(a0, j0 + u);
            float aj1 = rl_f(a1, j0 + u);
            aj[u] = (lane < 32) ? aj0 : aj1;                  // head = 2l/64
          }
          #pragma unroll
          for (int u = 0; u < 16; u++){
            ax += bf2f((unsigned short)(w[u] & 0xffffu)) * aj[u];
            ay += bf2f((unsigned short)(w[u] >> 16))     * aj[u];
          }
        }
        for (; j0 < cnt; j0 += 8){                 // padded tail (s=0, a=0 pads)
          unsigned w[8]; float aj[8];
          #pragma unroll
          for (int u = 0; u < 8; u++){
            int sj = __builtin_amdgcn_readlane(s, j0 + u);
            w[u] = fhb[(size_t)sj*64 + lane];
          }
          #pragma unroll
          for (int u = 0; u < 8; u++){
            float aj0 = rl_f(a0, j0 + u);
            float aj1 = rl_f(a1, j0 + u);
            aj[u] = (lane < 32) ? aj0 : aj1;
          }
          #pragma unroll
          for (int u = 0; u < 8; u++){
            ax += bf2f((unsigned short)(w[u] & 0xffffu)) * aj[u];
            ay += bf2f((unsigned short)(w[u] >> 16))     * aj[u];
          }
        }
      } else {
        const unsigned short* fh16 = (const unsigned short*)fhb;
        for (; j0 + 16 <= cnt; j0 += 16){
          unsigned short w[16]; float aj[16];
          #pragma unroll
          for (int u = 0; u < 16; u++){
            int sj = __builtin_amdgcn_readlane(s, j0 + u);
            w[u] = fh16[(size_t)sj*128 + lane];               // cols 0..63
          }
          #pragma unroll
          for (int u = 0; u < 16; u++) aj[u] = rl_f(a0, j0 + u);
          #pragma unroll
          for (int u = 0; u < 16; u++) ax += bf2f(w[u]) * aj[u];
        }
        for (; j0 < cnt; j0 += 8){
          unsigned short w[8]; float aj[8];
          #pragma unroll
          for (int u = 0; u < 8; u++){
            int sj = __builtin_amdgcn_readlane(s, j0 + u);
            w[u] = fh16[(size_t)sj*128 + lane];
          }
          #pragma unroll
          for (int u = 0; u < 8; u++) aj[u] = rl_f(a0, j0 + u);
          #pragma unroll
          for (int u = 0; u < 8; u++) ax += bf2f(w[u]) * aj[u];
        }
      }
    }
    if (H == 2){
      int c0 = lane*2;
      float o0 = ax + bias[c0], o1 = ay + bias[c0+1];
      if (res){ o0 += res[(size_t)n*128 + c0]; o1 += res[(size_t)n*128 + c0+1]; }
      if (act){ o0 = o0 > 0.f ? o0 : expm1f(o0); o1 = o1 > 0.f ? o1 : expm1f(o1); }
      *(float2*)(out + (size_t)n*out_ld + c0) = make_float2(o0, o1);
    } else {
      const unsigned short* fh16 = (const unsigned short*)fhb;
      float o = ax + bias[lane];
      if (res_from_fh) o += bf2f(fh16[(size_t)n*128 + 64 + lane]);
      out[(size_t)n*out_ld + lane] = o;
    }
  }
}

// ---- cooperative mega-kernel (LDS: 1KB scan buffer only) ----------------

__global__ __launch_bounds__(256, 4) void k_mega(
    const int* feat, const float* fv, const int* src, const int* dst,
    const float* emb,
    const float* W0, const float* al0, const float* ar0, const float* b0,
    const float* W1, const float* al1, const float* ar1, const float* b1,
    const float* W2, const float* al2, const float* ar2, const float* b2,
    const float* rW2,
    unsigned short* P1, float* P2, float* P3, float* elr,
    int* row_ptr, int* counts, int* cursor, unsigned short* ssrc, int* bsum,
    unsigned short* Wt0, unsigned short* Wt1, unsigned short* Wt2,
    float* out, int N, int E){
  __shared__ int si[256];
  cg::grid_group grid = cg::this_grid();
  const int t = threadIdx.x, bid = blockIdx.x, nb = gridDim.x;
  const int gtid = bid*256 + t, gsz = nb*256;

  // phase 0: zero counts+cursor (contiguous 2N) + weight prep
  for (int id = gtid; id < 2*N; id += gsz) counts[id] = 0;
  wprep_body(W0, W1, W2, rW2, Wt0, Wt1, Wt2, gtid, gsz);
  __threadfence(); grid.sync();

  // phase 1: histogram
  hist_body(dst, counts, E, gtid, gsz);
  __threadfence(); grid.sync();

  // phase 2: exclusive scan -> row_ptr
  const int SB = (N + 255)/256;
  if (bid < SB){
    int v = (gtid < N) ? counts[gtid] : 0;
    si[t] = v; __syncthreads();
    #pragma unroll
    for (int off = 1; off < 256; off <<= 1){
      int x = (t >= off) ? si[t-off] : 0;
      __syncthreads(); si[t] += x; __syncthreads();
    }
    if (gtid < N) row_ptr[gtid+1] = si[t];
    if (gtid == 0) row_ptr[0] = 0;
    if (t == 255) bsum[bid] = si[255];
  }
  __threadfence(); grid.sync();
  if (bid == 0){
    int v = (t < SB) ? bsum[t] : 0;
    si[t] = v; __syncthreads();
    #pragma unroll
    for (int off = 1; off < 256; off <<= 1){
      int x = (t >= off) ? si[t-off] : 0;
      __syncthreads(); si[t] += x; __syncthreads();
    }
    if (t < SB) bsum[t] = si[t] - v;
  }
  __threadfence(); grid.sync();
  if (bid > 0 && bid < SB && gtid < N) row_ptr[gtid+1] += bsum[bid];
  __threadfence(); grid.sync();

  // phase 3: scatter
  scatter_body(src, dst, row_ptr, cursor, ssrc, E, gtid, gsz);
  __threadfence(); grid.sync();

  // layers
  gemm_phase<64,2,0>(nullptr, feat, fv, emb, Wt0, al0, ar0, P1, elr, N, bid, nb, t);
  __threadfence(); grid.sync();
  agg_phase<2>((unsigned*)P1, elr, row_ptr, ssrc, b0, nullptr, 1, 0, P2, 128, N, bid, nb, t);
  __threadfence(); grid.sync();
  gemm_phase<128,2,1>(P2, nullptr, nullptr, nullptr, Wt1, al1, ar1, P1, elr, N, bid, nb, t);
  __threadfence(); grid.sync();
  agg_phase<2>((unsigned*)P1, elr, row_ptr, ssrc, b1, P2, 1, 0, P3, 128, N, bid, nb, t);
  __threadfence(); grid.sync();
  gemm_phase<128,1,1>(P3, nullptr, nullptr, nullptr, Wt2, al2, ar2, P1, elr, N, bid, nb, t);
  __threadfence(); grid.sync();
  agg_phase<1>((unsigned*)P1, elr, row_ptr, ssrc, b2, nullptr, 0, 1, out, 64, N, bid, nb, t);
}

// ---- fallback wrappers (R8-equivalent multi-dispatch path) ---------------

__global__ __launch_bounds__(256) void k_hist(const int* dst, int* counts, int E){
  hist_body(dst, counts, E, blockIdx.x*256 + threadIdx.x, gridDim.x*256);
}
__global__ __launch_bounds__(256) void k_scatter(const int* src, const int* dst,
    const int* row_ptr, int* cursor, unsigned short* ssrc, int E){
  scatter_body(src, dst, row_ptr, cursor, ssrc, E, blockIdx.x*256 + threadIdx.x, gridDim.x*256);
}
__global__ __launch_bounds__(256) void k_wprep(const float* W0, const float* W1,
    const float* W2, const float* rW2,
    unsigned short* Wt0, unsigned short* Wt1, unsigned short* Wt2){
  wprep_body(W0, W1, W2, rW2, Wt0, Wt1, Wt2, blockIdx.x*256 + threadIdx.x, gridDim.x*256);
}
__global__ void k_scan_local(const int* counts, int* row_ptr, int* bsum, int N){
  __shared__ int s[256];
  int t = threadIdx.x, g = blockIdx.x*256 + t;
  int v = (g < N) ? counts[g] : 0;
  s[t] = v; __syncthreads();
  #pragma unroll
  for (int off = 1; off < 256; off <<= 1){
    int x = (t >= off) ? s[t-off] : 0;
    __syncthreads(); s[t] += x; __syncthreads();
  }
  if (g < N) row_ptr[g+1] = s[t];
  if (g == 0 && t == 0) row_ptr[0] = 0;
  if (t == 255) bsum[blockIdx.x] = s[255];
}
__global__ void k_scan_top(int* bsum, int nb){
  __shared__ int s[256];
  int t = threadIdx.x;
  int v = (t < nb) ? bsum[t] : 0;
  s[t] = v; __syncthreads();
  #pragma unroll
  for (int off = 1; off < 256; off <<= 1){
    int x = (t >= off) ? s[t-off] : 0;
    __syncthreads(); s[t] += x; __syncthreads();
  }
  if (t < nb) bsum[t] = s[t] - v;
}
__global__ void k_scan_fix(int* row_ptr, const int* bsum, int N){
  int g = blockIdx.x*256 + threadIdx.x;
  if (g < N && blockIdx.x > 0) row_ptr[g+1] += bsum[blockIdx.x];
}
template<int IN, int H, int AMODE>
__global__ __launch_bounds__(256) void k_gemm(
    const float* hf, const int* feat, const float* fv, const float* emb,
    const unsigned short* Wt, const float* al, const float* ar,
    unsigned short* fhb, float* elr, int N){
  gemm_phase<IN,H,AMODE>(hf, feat, fv, emb, Wt, al, ar, fhb, elr, N,
                         blockIdx.x, gridDim.x, threadIdx.x);
}
template<int H>
__global__ __launch_bounds__(256) void k_agg(
    const unsigned* fhb, const float* elr, const int* row_ptr,
    const unsigned short* ssrc, const float* bias, const float* res,
    int act, int res_from_fh, float* out, int out_ld, int N){
  agg_phase<H>(fhb, elr, row_ptr, ssrc, bias, res, act, res_from_fh,
               out, out_ld, N, blockIdx.x, gridDim.x, threadIdx.x);
}

extern "C" void kernel_launch(void* const* d_in, const int* in_sizes, int n_in,
                              void* d_out, int out_size, void* d_ws, size_t ws_size,
                              hipStream_t stream) {
  const int*   feat = (const int*)  d_in[0];
  const float* fv   = (const float*)d_in[1];
  const int*   src  = (const int*)  d_in[2];
  const int*   dst  = (const int*)  d_in[3];
  const float* emb  = (const float*)d_in[4];
  const float* W0   = (const float*)d_in[5];
  const float* al0  = (const float*)d_in[6];
  const float* ar0  = (const float*)d_in[7];
  const float* b0   = (const float*)d_in[8];
  const float* W1   = (const float*)d_in[9];
  const float* al1  = (const float*)d_in[10];
  const float* ar1  = (const float*)d_in[11];
  const float* b1   = (const float*)d_in[12];
  const float* W2   = (const float*)d_in[13];
  const float* al2  = (const float*)d_in[14];
  const float* ar2  = (const float*)d_in[15];
  const float* b2   = (const float*)d_in[16];
  const float* rW2  = (const float*)d_in[17];
  int N = in_sizes[0] / 8;   // 50000
  int E = in_sizes[2];       // 800000

  size_t off = 0;
  auto alloc = [&](size_t bytes) -> void* {
    void* p = (char*)d_ws + off;
    off = (off + bytes + 255) & ~(size_t)255;
    return p;
  };
  unsigned short* P1 = (unsigned short*)alloc((size_t)N*128*sizeof(unsigned short)); // fhb
  float* P2     = (float*)alloc((size_t)N*128*sizeof(float));
  float* P3     = (float*)alloc((size_t)N*128*sizeof(float));
  float* elr    = (float*)alloc((size_t)N*4*sizeof(float));
  int* row_ptr  = (int*)alloc((size_t)(N+1)*sizeof(int));
  int* counts   = (int*)alloc((size_t)2*N*sizeof(int));
  int* cursor   = counts + N;
  unsigned short* ssrc = (unsigned short*)alloc((size_t)E*sizeof(unsigned short));
  int* bsum     = (int*)alloc(256*sizeof(int));
  unsigned short* Wt0 = (unsigned short*)alloc((size_t)128*64*sizeof(unsigned short));
  unsigned short* Wt1 = (unsigned short*)alloc((size_t)128*128*sizeof(unsigned short));
  unsigned short* Wt2 = (unsigned short*)alloc((size_t)128*128*sizeof(unsigned short));
  float* out = (float*)d_out;

  // ---- try cooperative single-launch path ----
  void* args[] = {
    &feat, &fv, &src, &dst, &emb,
    &W0, &al0, &ar0, &b0,
    &W1, &al1, &ar1, &b1,
    &W2, &al2, &ar2, &b2, &rW2,
    &P1, &P2, &P3, &elr,
    &row_ptr, &counts, &cursor, &ssrc, &bsum,
    &Wt0, &Wt1, &Wt2,
    &out, &N, &E
  };
  bool coop = false;
  int bpcu = 0;
  if (hipOccupancyMaxActiveBlocksPerMultiprocessor(&bpcu, (const void*)k_mega, 256, 0)
        == hipSuccess && bpcu >= 2){
    if (bpcu > 4) bpcu = 4;                 // 4 blocks/CU = 16 waves/CU cap
    int grid = bpcu * 256;                  // 256 CUs on MI355X
    if (hipLaunchCooperativeKernel((void*)k_mega, dim3(grid), dim3(256),
                                   args, 0, stream) == hipSuccess)
      coop = true;
  }
  if (coop) return;

  // ---- fallback: proven R8-style multi-dispatch path ----
  int nb1 = (N + 255) / 256;
  hipMemsetAsync(counts, 0, (size_t)2*N*sizeof(int), stream);
  k_hist<<<(E/4 + 255)/256, 256, 0, stream>>>(dst, counts, E);
  k_scan_local<<<nb1, 256, 0, stream>>>(counts, row_ptr, bsum, N);
  k_scan_top<<<1, 256, 0, stream>>>(bsum, nb1);
  k_scan_fix<<<nb1, 256, 0, stream>>>(row_ptr, bsum, N);
  k_scatter<<<(E/4 + 255)/256, 256, 0, stream>>>(src, dst, row_ptr, cursor, ssrc, E);
  k_wprep<<<(128*64 + 2*128*128 + 255)/256, 256, 0, stream>>>(
      W0, W1, W2, rW2, Wt0, Wt1, Wt2);

  int gt = (N + 63)/64;
  int nagg = (N + 3)/4;
  k_gemm<64,2,0><<<gt, 256, 0, stream>>>(nullptr, feat, fv, emb, Wt0, al0, ar0, P1, elr, N);
  k_agg<2><<<nagg, 256, 0, stream>>>((unsigned*)P1, elr, row_ptr, ssrc, b0, nullptr,
                                     1, 0, P2, 128, N);
  k_gemm<128,2,1><<<gt, 256, 0, stream>>>(P2, nullptr, nullptr, nullptr, Wt1, al1, ar1, P1, elr, N);
  k_agg<2><<<nagg, 256, 0, stream>>>((unsigned*)P1, elr, row_ptr, ssrc, b1, P2,
                                     1, 0, P3, 128, N);
  k_gemm<128,1,1><<<gt, 256, 0, stream>>>(P3, nullptr, nullptr, nullptr, Wt2, al2, ar2, P1, elr, N);
  k_agg<1><<<nagg, 256, 0, stream>>>((unsigned*)P1, elr, row_ptr, ssrc, b2, nullptr,
                                     0, 1, (float*)d_out, 64, N);
}